// Round 3
// baseline (29.066 us; speedup 1.0000x reference)
//
#include <hip/hip_runtime.h>

#define NN 4096
#define MM 4096
#define PP 32
#define TM 64    // rows per block (x1)
#define TN 128   // cols per block (x2)

// 256 threads, 4x8 microtile. LDS p-major tiles, stride 68/132 floats:
// - row byte stride (272/528) is 16B-aligned -> ds_read_b128 fragments
// - staging-write banks spread 4-way (free-ish), read conflicts <=4-way
// ~26 KB LDS/block -> 6 blocks/CU, 24 waves/CU resident.
__launch_bounds__(256, 4)
__global__ void eq_fused_kernel(const float* __restrict__ x1,
                                const float* __restrict__ x2,
                                const float* __restrict__ log_rho,
                                const float* __restrict__ log_sigma,
                                float* __restrict__ out) {
    __shared__ float As[PP][68];    // 64 rows used
    __shared__ float Bs[PP][132];   // 128 rows used
    __shared__ float xn_s[TM];
    __shared__ float yn_s[TN];

    const int bx = blockIdx.x;  // col tile
    const int by = blockIdx.y;  // row tile
    const int t  = threadIdx.x;

    // ---- Stage: float4 global loads, transposed scalar LDS writes ----
    // A tile: 64x32 = 512 float4s -> 2 per thread
#pragma unroll
    for (int k = 0; k < 2; ++k) {
        int idx4 = t + k * 256;
        int row  = idx4 >> 3;          // 0..63
        int pc   = (idx4 & 7) * 4;     // 0,4,...,28
        float4 v = *reinterpret_cast<const float4*>(&x1[(by * TM + row) * PP + pc]);
        As[pc + 0][row] = v.x;
        As[pc + 1][row] = v.y;
        As[pc + 2][row] = v.z;
        As[pc + 3][row] = v.w;
    }
    // B tile: 128x32 = 1024 float4s -> 4 per thread
#pragma unroll
    for (int k = 0; k < 4; ++k) {
        int idx4 = t + k * 256;
        int row  = idx4 >> 3;          // 0..127
        int pc   = (idx4 & 7) * 4;
        float4 v = *reinterpret_cast<const float4*>(&x2[(bx * TN + row) * PP + pc]);
        Bs[pc + 0][row] = v.x;
        Bs[pc + 1][row] = v.y;
        Bs[pc + 2][row] = v.z;
        Bs[pc + 3][row] = v.w;
    }
    __syncthreads();

    // ---- In-tile row norms (tiny phase; 2 lanes/bank = free) ----
    if (t < TM) {
        float s = 0.f;
#pragma unroll
        for (int p = 0; p < PP; ++p) s = fmaf(As[p][t], As[p][t], s);
        xn_s[t] = s;
    } else if (t < TM + TN) {
        int r = t - TM;
        float s = 0.f;
#pragma unroll
        for (int p = 0; p < PP; ++p) s = fmaf(Bs[p][r], Bs[p][r], s);
        yn_s[r] = s;
    }
    __syncthreads();

    const int tx = t & 15;   // 0..15 -> 8 cols each
    const int ty = t >> 4;   // 0..15 -> 4 rows each

    float acc[4][8] = {};
#pragma unroll 4
    for (int p = 0; p < PP; ++p) {
        float4 a  = *reinterpret_cast<const float4*>(&As[p][ty * 4]);
        float4 b0 = *reinterpret_cast<const float4*>(&Bs[p][tx * 8]);
        float4 b1 = *reinterpret_cast<const float4*>(&Bs[p][tx * 8 + 4]);
        float av[4] = {a.x, a.y, a.z, a.w};
        float bv[8] = {b0.x, b0.y, b0.z, b0.w, b1.x, b1.y, b1.z, b1.w};
#pragma unroll
        for (int i = 0; i < 4; ++i)
#pragma unroll
            for (int j = 0; j < 8; ++j)
                acc[i][j] = fmaf(av[i], bv[j], acc[i][j]);
    }

    // ---- Epilogue: d = (xn + yn - 2*dot) * inv_rho2; K = sigma*exp(-d/2) ----
    const float inv_rho2 = __expf(-2.f * log_rho[0]);
    const float sigma    = __expf(2.f * log_sigma[0]);
    const float m2ir2    = -2.f * inv_rho2;

    float yn[8];
#pragma unroll
    for (int j = 0; j < 8; ++j) yn[j] = yn_s[tx * 8 + j] * inv_rho2;

    const int col = bx * TN + tx * 8;
#pragma unroll
    for (int i = 0; i < 4; ++i) {
        const float xn = xn_s[ty * 4 + i] * inv_rho2;
        float r[8];
#pragma unroll
        for (int j = 0; j < 8; ++j) {
            float d = fmaf(m2ir2, acc[i][j], xn + yn[j]);
            d = fmaxf(d, 0.f);
            r[j] = sigma * __expf(-0.5f * d);
        }
        const int row = by * TM + ty * 4 + i;
        float4 o0 = {r[0], r[1], r[2], r[3]};
        float4 o1 = {r[4], r[5], r[6], r[7]};
        *reinterpret_cast<float4*>(&out[row * MM + col])     = o0;
        *reinterpret_cast<float4*>(&out[row * MM + col + 4]) = o1;
    }
}

extern "C" void kernel_launch(void* const* d_in, const int* in_sizes, int n_in,
                              void* d_out, int out_size, void* d_ws, size_t ws_size,
                              hipStream_t stream) {
    const float* x1        = (const float*)d_in[0];
    const float* x2        = (const float*)d_in[1];
    const float* log_rho   = (const float*)d_in[2];
    const float* log_sigma = (const float*)d_in[3];
    float* out = (float*)d_out;

    dim3 grid(MM / TN, NN / TM);   // 32 x 64 = 2048 blocks
    eq_fused_kernel<<<grid, 256, 0, stream>>>(x1, x2, log_rho, log_sigma, out);
}